// Round 14
// baseline (604.587 us; speedup 1.0000x reference)
//
#include <hip/hip_runtime.h>
#include <hip/hip_bf16.h>

#define Hh   64      // LSTM hidden
#define G4   256     // 4*H gate width
#define Dd   128     // input feature dim
#define Bsz  256     // batch
#define Tt   1024    // time steps
#define NOUT 10      // dense classes

typedef __bf16  bf16x8 __attribute__((ext_vector_type(8)));
typedef __bf16  bf16x4 __attribute__((ext_vector_type(4)));
typedef float   f32x4v __attribute__((ext_vector_type(4)));

// rho = 64g + 16w + 4kq + r  <->  original gate column = 64g + hidx with
// hidx = 32(w>>1) + 8kq + 4(w&1) + r.
__device__ __forceinline__ int rho_origcol(int rho) {
    const int g  = rho >> 6;
    const int s  = (rho >> 5) & 1;
    const int d2 = (rho >> 4) & 1;
    const int kq = (rho >> 2) & 3;
    const int dl = rho & 3;
    return g * 64 + (32 * s + 8 * kq + 4 * d2 + dl);
}

// xws layout (bf16): byte(b,t,rho) = (b>>4)<<23 + t*8192 + w_*2048 + g_*512
//                    + kq_*128 + (b&15)*8 + r_*2   with rho = 64g_+16w_+4kq_+r_.

__device__ __forceinline__ void gld_lds16(const void* g, void* l) {
    __builtin_amdgcn_global_load_lds(
        (const __attribute__((address_space(1))) unsigned int*)g,
        (__attribute__((address_space(3))) unsigned int*)l, 16, 0, 0);
}

// ---------------------------------------------------------------------------
// K0: Wt[rho][k] = bf16(scale * W[k][origcol]), bias2[rho] = scale*b + offs.
// ---------------------------------------------------------------------------
__global__ __launch_bounds__(128)
void k0_prep(const float* __restrict__ W, const float* __restrict__ b,
             __bf16* __restrict__ Wt, float* __restrict__ bias2) {
    const int rho = blockIdx.x;
    const int k   = threadIdx.x;
    const int col = rho_origcol(rho);
    const bool isg = ((rho >> 6) == 2);
    const float sc = isg ? 1.f : 0.2f;
    Wt[(size_t)rho * Dd + k] = (__bf16)(sc * W[(size_t)k * G4 + col]);
    if (k == 0) bias2[rho] = sc * b[col] + (isg ? 0.f : 0.5f);
}

// ---------------------------------------------------------------------------
// K1: xw = x @ Wt + bias2 via MFMA, stored into the k2-native xws layout.
// (verbatim from the passing R13 kernel)
// ---------------------------------------------------------------------------
#define K1_RT 8

__global__ __launch_bounds__(256)
void k1_mfma(const float* __restrict__ x, const __bf16* __restrict__ Wt,
             const float* __restrict__ bias, __bf16* __restrict__ xws) {
    const int tid = threadIdx.x;
    const int w   = tid >> 6;
    const int l   = tid & 63;
    const int r16 = l & 15;
    const int kq  = l >> 4;
    const size_t rowbase = (size_t)blockIdx.x * (16 * K1_RT);

    const int bb = (int)(rowbase >> 10);
    const size_t gm_base = ((size_t)(bb >> 4) << 23);
    const int lane_off = w * 512 + (r16 >> 2) * 128 + (bb & 15) * 8 + (r16 & 3) * 2;

    bf16x8 bfr[4][4];
    float  bval[4];
#pragma unroll
    for (int ct = 0; ct < 4; ++ct) {
        const int col = w * 64 + ct * 16 + r16;
        const __bf16* wp = Wt + (size_t)col * Dd + kq * 8;
#pragma unroll
        for (int kk = 0; kk < 4; ++kk)
            bfr[ct][kk] = *(const bf16x8*)(wp + kk * 32);
        bval[ct] = bias[col];
    }

    for (int rt = 0; rt < K1_RT; ++rt) {
        const size_t arow = rowbase + rt * 16 + r16;
        const float* xr = x + arow * Dd + kq * 8;
        bf16x8 afr[4];
#pragma unroll
        for (int kk = 0; kk < 4; ++kk) {
            const float4 lo = *(const float4*)(xr + kk * 32);
            const float4 hi = *(const float4*)(xr + kk * 32 + 4);
            afr[kk][0] = (__bf16)lo.x; afr[kk][1] = (__bf16)lo.y;
            afr[kk][2] = (__bf16)lo.z; afr[kk][3] = (__bf16)lo.w;
            afr[kk][4] = (__bf16)hi.x; afr[kk][5] = (__bf16)hi.y;
            afr[kk][6] = (__bf16)hi.z; afr[kk][7] = (__bf16)hi.w;
        }
        f32x4v acc[4];
#pragma unroll
        for (int ct = 0; ct < 4; ++ct)
            acc[ct] = (f32x4v){bval[ct], bval[ct], bval[ct], bval[ct]};
#pragma unroll
        for (int ct = 0; ct < 4; ++ct)
#pragma unroll
            for (int kk = 0; kk < 4; ++kk)
                acc[ct] = __builtin_amdgcn_mfma_f32_16x16x32_bf16(
                              afr[kk], bfr[ct][kk], acc[ct], 0, 0, 0);

        const int trow0 = (int)((rowbase + rt * 16 + kq * 4) & 1023);
#pragma unroll
        for (int ct = 0; ct < 4; ++ct) {
#pragma unroll
            for (int rr = 0; rr < 4; ++rr) {
                char* dst = (char*)xws + gm_base + (size_t)(trow0 + rr) * 8192
                            + (size_t)ct * 2048 + lane_off;
                *(__bf16*)dst = (__bf16)acc[ct][rr];
            }
        }
    }
}

// ---------------------------------------------------------------------------
// K2: LSTM scan, 4 cooperating waves per 16-batch group, 1 group/block,
// 16 blocks. R13 superstep/DMA structure; step body re-scheduled:
//  - post-barrier critical path: bh reads -> PARALLEL MFMA pair (+add
//    folded into gates) -> gates -> hx write
//  - ring prestage reads issued right after bh reads (retire during MFMA)
//  - accN unpack runs pre-barrier in the write-drain slot
//  - barrier is a bare asm s_barrier with "memory" clobber (C-level fence,
//    no sched_barrier walls -> compiler may move register work across)
// ---------------------------------------------------------------------------
#define SST 8   // steps per superstep

__global__ __launch_bounds__(256, 1)
void k2_scan(const __bf16* __restrict__ xws, const float* __restrict__ U,
             float* __restrict__ hout) {
    const int tid = threadIdx.x;
    const int w   = tid >> 6;       // wave 0..3
    const int l   = tid & 63;
    const int kq  = l >> 4;
    const int m   = l & 15;
    const int s_  = w >> 1, d2 = w & 1;
    const int G   = blockIdx.x;     // group 0..15

    __shared__ __align__(16) unsigned char ring[4][2][SST][2048];  // 128KB
    __shared__ __align__(16) __bf16 hx[2][16][72];                 // 4.5KB

    // A-frags: au[g][ks][j] = sc_g * U[32ks + 8kq + j][origcol(64g+16w+m)]
    bf16x8 au[4][2];
#pragma unroll
    for (int g = 0; g < 4; ++g) {
        const float sc = (g == 2) ? 1.f : 0.2f;
        const int col = rho_origcol(64 * g + 16 * w + m);
#pragma unroll
        for (int ks = 0; ks < 2; ++ks)
#pragma unroll
            for (int j = 0; j < 8; ++j)
                au[g][ks][j] = (__bf16)(sc * U[(size_t)(ks * 32 + kq * 8 + j) * G4 + col]);
    }

    float c4[4]  = {0.f, 0.f, 0.f, 0.f};
    float hv4[4] = {0.f, 0.f, 0.f, 0.f};
    const f32x4v zC = {0.f, 0.f, 0.f, 0.f};   // loop-invariant zero C operand

    // zero hx[1] (read by the very first step, rp = 1)
    {
        const bf16x4 z4 = {(__bf16)0.f, (__bf16)0.f, (__bf16)0.f, (__bf16)0.f};
        *(bf16x4*)&hx[1][m][32 * s_ + 8 * kq + 4 * d2] = z4;
    }

    const char* gl = (const char*)xws + ((size_t)G << 23)
                     + (size_t)w * 2048 + (size_t)l * 16;

    // prologue: issue buf0 (steps 0..7) and buf1 (steps 8..15) -> 32 in flight
#pragma unroll
    for (int buf = 0; buf < 2; ++buf)
#pragma unroll
        for (int stp = 0; stp < SST; ++stp)
#pragma unroll
            for (int gg = 0; gg < 2; ++gg)
                gld_lds16(gl + (size_t)(buf * SST + stp) * 8192 + gg * 1024,
                          &ring[w][buf][stp][gg * 1024]);
    __syncthreads();   // once: drains prologue DMAs + publishes hx[1] zeros

    uint2  dz[4];
    f32x4v accN[4];
    bf16x8 bh0, bh1;

    for (int S = 0; S < Tt / SST; ++S) {
        const int cur = S & 1;

        // buf[cur] ready when <=16 outstanding (only next superstep's remain)
        asm volatile("s_waitcnt vmcnt(16)" ::: "memory");
        __builtin_amdgcn_sched_barrier(0);

        // superstep-top C-init for stp 0 (once per 8 steps)
#pragma unroll
        for (int g = 0; g < 4; ++g)
            dz[g] = *(const uint2*)&ring[w][cur][0][g * 512 + kq * 128 + m * 8];
#pragma unroll
        for (int g = 0; g < 4; ++g) {
            accN[g][0] = __builtin_bit_cast(float, dz[g].x << 16);
            accN[g][1] = __builtin_bit_cast(float, dz[g].x & 0xFFFF0000u);
            accN[g][2] = __builtin_bit_cast(float, dz[g].y << 16);
            accN[g][3] = __builtin_bit_cast(float, dz[g].y & 0xFFFF0000u);
        }

#pragma unroll
        for (int stp = 0; stp < SST; ++stp) {
            const int rp = (stp + 1) & 1;   // parity written by previous step

            // ---- post-barrier critical path: bh reads -> MFMA (parallel)
            bh0 = *(const bf16x8*)&hx[rp][m][8 * kq];
            bh1 = *(const bf16x8*)&hx[rp][m][32 + 8 * kq];

            // prestage next step's C reads (wave-private ring; DMA complete)
            if (stp < SST - 1) {
#pragma unroll
                for (int g = 0; g < 4; ++g)
                    dz[g] = *(const uint2*)&ring[w][cur][stp + 1][g * 512
                                                                  + kq * 128 + m * 8];
            }

            f32x4v acc[4], acc2[4];
#pragma unroll
            for (int g = 0; g < 4; ++g) {
                acc[g]  = __builtin_amdgcn_mfma_f32_16x16x32_bf16(au[g][0], bh0, accN[g], 0, 0, 0);
                acc2[g] = __builtin_amdgcn_mfma_f32_16x16x32_bf16(au[g][1], bh1, zC,      0, 0, 0);
            }

            bf16x4 hb;
#pragma unroll
            for (int r = 0; r < 4; ++r) {
                const float gi = __builtin_amdgcn_fmed3f(acc[0][r] + acc2[0][r], 0.f, 1.f);
                const float gf = __builtin_amdgcn_fmed3f(acc[1][r] + acc2[1][r], 0.f, 1.f);
                const float gg = fmaxf(acc[2][r] + acc2[2][r], 0.f);
                const float go = __builtin_amdgcn_fmed3f(acc[3][r] + acc2[3][r], 0.f, 1.f);
                c4[r] = fmaf(gf, c4[r], gi * gg);
                hv4[r] = go * fmaxf(c4[r], 0.f);
                hb[r] = (__bf16)hv4[r];
            }

            // ---- publish h
            *(bf16x4*)&hx[stp & 1][m][32 * s_ + 8 * kq + 4 * d2] = hb;

            // ---- drain LDS (prestage reads retired long ago; waits on write)
            asm volatile("s_waitcnt lgkmcnt(0)" ::: "memory");

            // ---- unpack accN for next step in the drain/barrier slot
            if (stp < SST - 1) {
#pragma unroll
                for (int g = 0; g < 4; ++g) {
                    accN[g][0] = __builtin_bit_cast(float, dz[g].x << 16);
                    accN[g][1] = __builtin_bit_cast(float, dz[g].x & 0xFFFF0000u);
                    accN[g][2] = __builtin_bit_cast(float, dz[g].y << 16);
                    accN[g][3] = __builtin_bit_cast(float, dz[g].y & 0xFFFF0000u);
                }
            }

            asm volatile("s_barrier" ::: "memory");
        }

        // ---- issue superstep S+2 into buf[cur] (reads long retired)
        {
            int tn0 = (S + 2) * SST;
            if (tn0 > Tt - SST) tn0 = Tt - SST;
            const char* p = gl + (size_t)tn0 * 8192;
#pragma unroll
            for (int stp = 0; stp < SST; ++stp)
#pragma unroll
                for (int gg = 0; gg < 2; ++gg)
                    gld_lds16(p + (size_t)stp * 8192 + gg * 1024,
                              &ring[w][cur][stp][gg * 1024]);
        }
    }

    // final h (f32, in registers): hidx = 32s_ + 8kq + 4d2 + r
#pragma unroll
    for (int r = 0; r < 4; ++r)
        hout[(size_t)(G * 16 + m) * Hh + 32 * s_ + 8 * kq + 4 * d2 + r] = hv4[r];
}

// ---------------------------------------------------------------------------
// K3: out[r,:] = softmax(h[r,:] @ Wd + bd). One block, thread = batch row.
// ---------------------------------------------------------------------------
__global__ __launch_bounds__(256)
void k3_dense(const float* __restrict__ hin, const float* __restrict__ Wd,
              const float* __restrict__ bd, float* __restrict__ out) {
    __shared__ float wd[Hh * NOUT];
    __shared__ float bds[NOUT];
    for (int i = threadIdx.x; i < Hh * NOUT; i += blockDim.x) wd[i] = Wd[i];
    if (threadIdx.x < NOUT) bds[threadIdx.x] = bd[threadIdx.x];
    __syncthreads();

    const int r = threadIdx.x;
    if (r < Bsz) {
        float hrow[Hh];
#pragma unroll
        for (int j = 0; j < Hh; ++j) hrow[j] = hin[(size_t)r * Hh + j];
        float logits[NOUT];
#pragma unroll
        for (int o = 0; o < NOUT; ++o) {
            float acc = bds[o];
#pragma unroll
            for (int j = 0; j < Hh; ++j) acc = fmaf(hrow[j], wd[j * NOUT + o], acc);
            logits[o] = acc;
        }
        float mx = logits[0];
#pragma unroll
        for (int o = 1; o < NOUT; ++o) mx = fmaxf(mx, logits[o]);
        float s = 0.f;
#pragma unroll
        for (int o = 0; o < NOUT; ++o) { logits[o] = expf(logits[o] - mx); s += logits[o]; }
        const float inv = 1.f / s;
#pragma unroll
        for (int o = 0; o < NOUT; ++o) out[(size_t)r * NOUT + o] = logits[o] * inv;
    }
}

// ---------------------------------------------------------------------------
extern "C" void kernel_launch(void* const* d_in, const int* in_sizes, int n_in,
                              void* d_out, int out_size, void* d_ws, size_t ws_size,
                              hipStream_t stream) {
    const float* x  = (const float*)d_in[0];
    const float* W  = (const float*)d_in[1];
    const float* U  = (const float*)d_in[2];
    const float* b  = (const float*)d_in[3];
    const float* Wd = (const float*)d_in[4];
    const float* bd = (const float*)d_in[5];
    float* out = (float*)d_out;

    const size_t xw_bytes = (size_t)Bsz * Tt * G4 * sizeof(__bf16);   // 128 MiB
    __bf16* xws   = (__bf16*)d_ws;
    float*  hbuf  = (float*)((char*)d_ws + xw_bytes);                 // 64 KB
    __bf16* Wt    = (__bf16*)((char*)hbuf + (size_t)Bsz * Hh * sizeof(float));
    float*  bias2 = (float*)((char*)Wt + (size_t)G4 * Dd * sizeof(__bf16));

    k0_prep<<<G4, Dd, 0, stream>>>(W, b, Wt, bias2);
    k1_mfma<<<(Bsz * Tt) / (16 * K1_RT), 256, 0, stream>>>(x, Wt, bias2, xws);
    k2_scan<<<Bsz / 16, 256, 0, stream>>>(xws, U, hbuf);
    k3_dense<<<1, 256, 0, stream>>>(hbuf, Wd, bd, out);
}

// Round 15
// 592.144 us; speedup vs baseline: 1.0210x; 1.0210x over previous
//
#include <hip/hip_runtime.h>
#include <hip/hip_bf16.h>

#define Hh   64      // LSTM hidden
#define G4   256     // 4*H gate width
#define Dd   128     // input feature dim
#define Bsz  256     // batch
#define Tt   1024    // time steps
#define NOUT 10      // dense classes

typedef __bf16  bf16x8 __attribute__((ext_vector_type(8)));
typedef __bf16  bf16x4 __attribute__((ext_vector_type(4)));
typedef float   f32x4v __attribute__((ext_vector_type(4)));

// rho = 64g + 16w + 4kq + r  <->  original gate column = 64g + hidx with
// hidx = 32(w>>1) + 8kq + 4(w&1) + r.
__device__ __forceinline__ int rho_origcol(int rho) {
    const int g  = rho >> 6;
    const int s  = (rho >> 5) & 1;
    const int d2 = (rho >> 4) & 1;
    const int kq = (rho >> 2) & 3;
    const int dl = rho & 3;
    return g * 64 + (32 * s + 8 * kq + 4 * d2 + dl);
}

// xws layout (bf16): byte(b,t,rho) = (b>>4)<<23 + t*8192 + w_*2048 + g_*512
//                    + kq_*128 + (b&15)*8 + r_*2   with rho = 64g_+16w_+4kq_+r_.

__device__ __forceinline__ void gld_lds16(const void* g, void* l) {
    __builtin_amdgcn_global_load_lds(
        (const __attribute__((address_space(1))) unsigned int*)g,
        (__attribute__((address_space(3))) unsigned int*)l, 16, 0, 0);
}

// ---------------------------------------------------------------------------
// K0: Wt[rho][k] = bf16(scale * W[k][origcol]), bias2[rho] = scale*b + offs.
// ---------------------------------------------------------------------------
__global__ __launch_bounds__(128)
void k0_prep(const float* __restrict__ W, const float* __restrict__ b,
             __bf16* __restrict__ Wt, float* __restrict__ bias2) {
    const int rho = blockIdx.x;
    const int k   = threadIdx.x;
    const int col = rho_origcol(rho);
    const bool isg = ((rho >> 6) == 2);
    const float sc = isg ? 1.f : 0.2f;
    Wt[(size_t)rho * Dd + k] = (__bf16)(sc * W[(size_t)k * G4 + col]);
    if (k == 0) bias2[rho] = sc * b[col] + (isg ? 0.f : 0.5f);
}

// ---------------------------------------------------------------------------
// K1: z^T = Wt . x^T + bias2 via mfma_f32_16x16x32_bf16, OPERAND-SWAPPED so
// D[rho][t]: lane (kq,r16) holds rho quad {64w1+16rti+4kq+0..3} for t-col
// r16 -> one aligned 8B (bf16x4) store per (tt,rti): 32 stores/lane vs the
// old 128 scalar 2B stores. A = Wt rows (resident), B = x rows (same global
// load pattern / redundancy as before). Block = 4 waves, 128 t x 256 rho.
// ---------------------------------------------------------------------------
__global__ __launch_bounds__(256)
void k1_mfma(const float* __restrict__ x, const __bf16* __restrict__ Wt,
             const float* __restrict__ bias, __bf16* __restrict__ xws) {
    const int tid = threadIdx.x;
    const int w1  = tid >> 6;      // wave: owns rho in [64w1, 64w1+64)
    const int l   = tid & 63;
    const int r16 = l & 15;        // A row (rho%16) / B col / D col (t%16)
    const int kq  = l >> 4;        // k-quad; also D rho-quad index
    const size_t rowbase = (size_t)blockIdx.x * 128;   // 128 t of one batch

    const int bb = (int)(rowbase >> 10);               // batch (uniform)
    const size_t gm_base = ((size_t)(bb >> 4) << 23) + (size_t)(bb & 15) * 8;

    // A-frags (resident): aw[rti][ks] = Wt[64w1+16rti+r16][32ks + kq*8 + j]
    bf16x8 aw[4][4];
#pragma unroll
    for (int rti = 0; rti < 4; ++rti) {
        const __bf16* wp = Wt + (size_t)(64 * w1 + 16 * rti + r16) * Dd + kq * 8;
#pragma unroll
        for (int ks = 0; ks < 4; ++ks)
            aw[rti][ks] = *(const bf16x8*)(wp + ks * 32);
    }
    // bias quads: bv[rti] = bias2[64w1 + 16rti + 4kq + 0..3]
    float4 bv[4];
#pragma unroll
    for (int rti = 0; rti < 4; ++rti)
        bv[rti] = *(const float4*)&bias[64 * w1 + 16 * rti + 4 * kq];

    for (int tt = 0; tt < 8; ++tt) {
        // B-frags: x[t = rowbase + 16tt + r16][32ks + kq*8 + j], f32 -> bf16
        const float* xr = x + (rowbase + tt * 16 + r16) * Dd + kq * 8;
        bf16x8 bx[4];
#pragma unroll
        for (int ks = 0; ks < 4; ++ks) {
            const float4 lo = *(const float4*)(xr + ks * 32);
            const float4 hi = *(const float4*)(xr + ks * 32 + 4);
            bx[ks][0] = (__bf16)lo.x; bx[ks][1] = (__bf16)lo.y;
            bx[ks][2] = (__bf16)lo.z; bx[ks][3] = (__bf16)lo.w;
            bx[ks][4] = (__bf16)hi.x; bx[ks][5] = (__bf16)hi.y;
            bx[ks][6] = (__bf16)hi.z; bx[ks][7] = (__bf16)hi.w;
        }

        const size_t trow = rowbase + tt * 16 + r16;   // global flat row
        const size_t tbyte = gm_base + (size_t)(trow & 1023) * 8192
                             + (size_t)w1 * 512 + (size_t)kq * 128;

#pragma unroll
        for (int rti = 0; rti < 4; ++rti) {
            f32x4v acc = {bv[rti].x, bv[rti].y, bv[rti].z, bv[rti].w};
#pragma unroll
            for (int ks = 0; ks < 4; ++ks)
                acc = __builtin_amdgcn_mfma_f32_16x16x32_bf16(
                          aw[rti][ks], bx[ks], acc, 0, 0, 0);
            bf16x4 pk;
            pk[0] = (__bf16)acc[0]; pk[1] = (__bf16)acc[1];
            pk[2] = (__bf16)acc[2]; pk[3] = (__bf16)acc[3];
            *(bf16x4*)((char*)xws + tbyte + (size_t)rti * 2048) = pk;
        }
    }
}

// ---------------------------------------------------------------------------
// K2: LSTM scan, 4 cooperating waves per 16-batch group, 1 group/block,
// 16 blocks. (Verbatim from the best-passing R13 kernel: superstep DMA ring,
// counted vmcnt(16), prestage + lgkmcnt(4), fmed3 gates, sched-fenced
// raw barrier.)
// ---------------------------------------------------------------------------
#define SST 8   // steps per superstep

__global__ __launch_bounds__(256, 1)
void k2_scan(const __bf16* __restrict__ xws, const float* __restrict__ U,
             float* __restrict__ hout) {
    const int tid = threadIdx.x;
    const int w   = tid >> 6;       // wave 0..3
    const int l   = tid & 63;
    const int kq  = l >> 4;
    const int m   = l & 15;
    const int s_  = w >> 1, d2 = w & 1;
    const int G   = blockIdx.x;     // group 0..15

    __shared__ __align__(16) unsigned char ring[4][2][SST][2048];  // 128KB
    __shared__ __align__(16) __bf16 hx[2][16][72];                 // 4.5KB

    bf16x8 au[4][2];
#pragma unroll
    for (int g = 0; g < 4; ++g) {
        const float sc = (g == 2) ? 1.f : 0.2f;
        const int col = rho_origcol(64 * g + 16 * w + m);
#pragma unroll
        for (int ks = 0; ks < 2; ++ks)
#pragma unroll
            for (int j = 0; j < 8; ++j)
                au[g][ks][j] = (__bf16)(sc * U[(size_t)(ks * 32 + kq * 8 + j) * G4 + col]);
    }

    float c4[4]  = {0.f, 0.f, 0.f, 0.f};
    float hv4[4] = {0.f, 0.f, 0.f, 0.f};

    // zero hx[1] (read by the very first step, rp = 1)
    {
        const bf16x4 z4 = {(__bf16)0.f, (__bf16)0.f, (__bf16)0.f, (__bf16)0.f};
        *(bf16x4*)&hx[1][m][32 * s_ + 8 * kq + 4 * d2] = z4;
    }

    const char* gl = (const char*)xws + ((size_t)G << 23)
                     + (size_t)w * 2048 + (size_t)l * 16;

    // prologue: issue buf0 (steps 0..7) and buf1 (steps 8..15) -> 32 in flight
#pragma unroll
    for (int buf = 0; buf < 2; ++buf)
#pragma unroll
        for (int stp = 0; stp < SST; ++stp)
#pragma unroll
            for (int gg = 0; gg < 2; ++gg)
                gld_lds16(gl + (size_t)(buf * SST + stp) * 8192 + gg * 1024,
                          &ring[w][buf][stp][gg * 1024]);
    __syncthreads();   // once: drains prologue DMAs + publishes hx[1] zeros

    uint2  dz[4];
    f32x4v accN[4];
    bf16x8 bh0, bh1;

    for (int S = 0; S < Tt / SST; ++S) {
        const int cur = S & 1;

        asm volatile("s_waitcnt vmcnt(16)" ::: "memory");
        __builtin_amdgcn_sched_barrier(0);

        // superstep-top C-init for stp 0
#pragma unroll
        for (int g = 0; g < 4; ++g)
            dz[g] = *(const uint2*)&ring[w][cur][0][g * 512 + kq * 128 + m * 8];
#pragma unroll
        for (int g = 0; g < 4; ++g) {
            accN[g][0] = __builtin_bit_cast(float, dz[g].x << 16);
            accN[g][1] = __builtin_bit_cast(float, dz[g].x & 0xFFFF0000u);
            accN[g][2] = __builtin_bit_cast(float, dz[g].y << 16);
            accN[g][3] = __builtin_bit_cast(float, dz[g].y & 0xFFFF0000u);
        }

#pragma unroll
        for (int stp = 0; stp < SST; ++stp) {
            const int rp = (stp + 1) & 1;

            bh0 = *(const bf16x8*)&hx[rp][m][8 * kq];
            bh1 = *(const bf16x8*)&hx[rp][m][32 + 8 * kq];

            f32x4v acc[4];
#pragma unroll
            for (int g = 0; g < 4; ++g) {
                acc[g] = __builtin_amdgcn_mfma_f32_16x16x32_bf16(au[g][0], bh0, accN[g], 0, 0, 0);
                acc[g] = __builtin_amdgcn_mfma_f32_16x16x32_bf16(au[g][1], bh1, acc[g], 0, 0, 0);
            }

            bf16x4 hb;
#pragma unroll
            for (int r = 0; r < 4; ++r) {
                const float gi = __builtin_amdgcn_fmed3f(acc[0][r], 0.f, 1.f);
                const float gf = __builtin_amdgcn_fmed3f(acc[1][r], 0.f, 1.f);
                const float gg = fmaxf(acc[2][r], 0.f);
                const float go = __builtin_amdgcn_fmed3f(acc[3][r], 0.f, 1.f);
                c4[r] = fmaf(gf, c4[r], gi * gg);
                hv4[r] = go * fmaxf(c4[r], 0.f);
                hb[r] = (__bf16)hv4[r];
            }

            *(bf16x4*)&hx[stp & 1][m][32 * s_ + 8 * kq + 4 * d2] = hb;

            if (stp < SST - 1) {
#pragma unroll
                for (int g = 0; g < 4; ++g)
                    dz[g] = *(const uint2*)&ring[w][cur][stp + 1][g * 512
                                                                  + kq * 128 + m * 8];
                asm volatile("s_waitcnt lgkmcnt(4)" ::: "memory");
            } else {
                asm volatile("s_waitcnt lgkmcnt(0)" ::: "memory");
            }
            __builtin_amdgcn_sched_barrier(0);
            __builtin_amdgcn_s_barrier();
            __builtin_amdgcn_sched_barrier(0);

            if (stp < SST - 1) {
#pragma unroll
                for (int g = 0; g < 4; ++g) {
                    accN[g][0] = __builtin_bit_cast(float, dz[g].x << 16);
                    accN[g][1] = __builtin_bit_cast(float, dz[g].x & 0xFFFF0000u);
                    accN[g][2] = __builtin_bit_cast(float, dz[g].y << 16);
                    accN[g][3] = __builtin_bit_cast(float, dz[g].y & 0xFFFF0000u);
                }
            }
        }

        // issue superstep S+2 into buf[cur]
        {
            int tn0 = (S + 2) * SST;
            if (tn0 > Tt - SST) tn0 = Tt - SST;
            const char* p = gl + (size_t)tn0 * 8192;
#pragma unroll
            for (int stp = 0; stp < SST; ++stp)
#pragma unroll
                for (int gg = 0; gg < 2; ++gg)
                    gld_lds16(p + (size_t)stp * 8192 + gg * 1024,
                              &ring[w][cur][stp][gg * 1024]);
        }
    }

#pragma unroll
    for (int r = 0; r < 4; ++r)
        hout[(size_t)(G * 16 + m) * Hh + 32 * s_ + 8 * kq + 4 * d2 + r] = hv4[r];
}

// ---------------------------------------------------------------------------
// K3: out[r,:] = softmax(h[r,:] @ Wd + bd). One block, thread = batch row.
// ---------------------------------------------------------------------------
__global__ __launch_bounds__(256)
void k3_dense(const float* __restrict__ hin, const float* __restrict__ Wd,
              const float* __restrict__ bd, float* __restrict__ out) {
    __shared__ float wd[Hh * NOUT];
    __shared__ float bds[NOUT];
    for (int i = threadIdx.x; i < Hh * NOUT; i += blockDim.x) wd[i] = Wd[i];
    if (threadIdx.x < NOUT) bds[threadIdx.x] = bd[threadIdx.x];
    __syncthreads();

    const int r = threadIdx.x;
    if (r < Bsz) {
        float hrow[Hh];
#pragma unroll
        for (int j = 0; j < Hh; ++j) hrow[j] = hin[(size_t)r * Hh + j];
        float logits[NOUT];
#pragma unroll
        for (int o = 0; o < NOUT; ++o) {
            float acc = bds[o];
#pragma unroll
            for (int j = 0; j < Hh; ++j) acc = fmaf(hrow[j], wd[j * NOUT + o], acc);
            logits[o] = acc;
        }
        float mx = logits[0];
#pragma unroll
        for (int o = 1; o < NOUT; ++o) mx = fmaxf(mx, logits[o]);
        float s = 0.f;
#pragma unroll
        for (int o = 0; o < NOUT; ++o) { logits[o] = expf(logits[o] - mx); s += logits[o]; }
        const float inv = 1.f / s;
#pragma unroll
        for (int o = 0; o < NOUT; ++o) out[(size_t)r * NOUT + o] = logits[o] * inv;
    }
}

// ---------------------------------------------------------------------------
extern "C" void kernel_launch(void* const* d_in, const int* in_sizes, int n_in,
                              void* d_out, int out_size, void* d_ws, size_t ws_size,
                              hipStream_t stream) {
    const float* x  = (const float*)d_in[0];
    const float* W  = (const float*)d_in[1];
    const float* U  = (const float*)d_in[2];
    const float* b  = (const float*)d_in[3];
    const float* Wd = (const float*)d_in[4];
    const float* bd = (const float*)d_in[5];
    float* out = (float*)d_out;

    const size_t xw_bytes = (size_t)Bsz * Tt * G4 * sizeof(__bf16);   // 128 MiB
    __bf16* xws   = (__bf16*)d_ws;
    float*  hbuf  = (float*)((char*)d_ws + xw_bytes);                 // 64 KB
    __bf16* Wt    = (__bf16*)((char*)hbuf + (size_t)Bsz * Hh * sizeof(float));
    float*  bias2 = (float*)((char*)Wt + (size_t)G4 * Dd * sizeof(__bf16));

    k0_prep<<<G4, Dd, 0, stream>>>(W, b, Wt, bias2);
    k1_mfma<<<(Bsz * Tt) / 128, 256, 0, stream>>>(x, Wt, bias2, xws);
    k2_scan<<<Bsz / 16, 256, 0, stream>>>(xws, U, hbuf);
    k3_dense<<<1, 256, 0, stream>>>(hbuf, Wd, bd, out);
}

// Round 16
// 547.502 us; speedup vs baseline: 1.1043x; 1.0815x over previous
//
#include <hip/hip_runtime.h>
#include <hip/hip_bf16.h>

#define Hh   64      // LSTM hidden
#define G4   256     // 4*H gate width
#define Dd   128     // input feature dim
#define Bsz  256     // batch
#define Tt   1024    // time steps
#define NOUT 10      // dense classes

typedef __bf16  bf16x8 __attribute__((ext_vector_type(8)));
typedef __bf16  bf16x4 __attribute__((ext_vector_type(4)));
typedef float   f32x4v __attribute__((ext_vector_type(4)));

// rho = 64g + 16w + 4kq + r  <->  original gate column = 64g + hidx with
// hidx = 32(w>>1) + 8kq + 4(w&1) + r.
__device__ __forceinline__ int rho_origcol(int rho) {
    const int g  = rho >> 6;
    const int s  = (rho >> 5) & 1;
    const int d2 = (rho >> 4) & 1;
    const int kq = (rho >> 2) & 3;
    const int dl = rho & 3;
    return g * 64 + (32 * s + 8 * kq + 4 * d2 + dl);
}

// xw layout: NATURAL [b][t][rho] bf16 -> byte = b*524288 + t*512 + rho*2.
// k2 gathers per step via global_load_lds with PER-LANE global source
// addresses (m104/m173): DMA instr i, lane l writes LDS base+i*1024+l*16;
// decompose m' = 2i+(l>>5), p = l&31, and fetch chunk sch = (p - m') & 31
// of batch 16G+m' -> LDS layout [m'][ (sch+m')&31 ]*16 (swizzled, so the
// C-init b64 reads sit at the 4-access/bank floor).

__device__ __forceinline__ void gld_lds16(const void* g, void* l) {
    __builtin_amdgcn_global_load_lds(
        (const __attribute__((address_space(1))) unsigned int*)g,
        (__attribute__((address_space(3))) unsigned int*)l, 16, 0, 0);
}

// ---------------------------------------------------------------------------
// K0: Wt[rho][k] = bf16(scale * W[k][origcol]), bias2[rho] = scale*b + offs.
// ---------------------------------------------------------------------------
__global__ __launch_bounds__(128)
void k0_prep(const float* __restrict__ W, const float* __restrict__ b,
             __bf16* __restrict__ Wt, float* __restrict__ bias2) {
    const int rho = blockIdx.x;
    const int k   = threadIdx.x;
    const int col = rho_origcol(rho);
    const bool isg = ((rho >> 6) == 2);
    const float sc = isg ? 1.f : 0.2f;
    Wt[(size_t)rho * Dd + k] = (__bf16)(sc * W[(size_t)k * G4 + col]);
    if (k == 0) bias2[rho] = sc * b[col] + (isg ? 0.f : 0.5f);
}

// ---------------------------------------------------------------------------
// K1: xw = x @ Wt + bias2 via MFMA, NATURAL [row][rho] store (proven R2/R3
// kernel: lanes with same kq store 16 consecutive rho = 32B segments).
// ---------------------------------------------------------------------------
#define K1_RT 8   // 128 rows/block

__global__ __launch_bounds__(256)
void k1_mfma(const float* __restrict__ x, const __bf16* __restrict__ Wt,
             const float* __restrict__ bias, __bf16* __restrict__ xw) {
    const int tid = threadIdx.x;
    const int w   = tid >> 6;
    const int l   = tid & 63;
    const int r16 = l & 15;
    const int kq  = l >> 4;
    const size_t rowbase = (size_t)blockIdx.x * (16 * K1_RT);

    bf16x8 bfr[4][4];
    float  bval[4];
#pragma unroll
    for (int ct = 0; ct < 4; ++ct) {
        const int col = w * 64 + ct * 16 + r16;
        const __bf16* wp = Wt + (size_t)col * Dd + kq * 8;
#pragma unroll
        for (int kk = 0; kk < 4; ++kk)
            bfr[ct][kk] = *(const bf16x8*)(wp + kk * 32);
        bval[ct] = bias[col];
    }

    for (int rt = 0; rt < K1_RT; ++rt) {
        const size_t arow = rowbase + rt * 16 + r16;
        const float* xr = x + arow * Dd + kq * 8;
        bf16x8 afr[4];
#pragma unroll
        for (int kk = 0; kk < 4; ++kk) {
            const float4 lo = *(const float4*)(xr + kk * 32);
            const float4 hi = *(const float4*)(xr + kk * 32 + 4);
            afr[kk][0] = (__bf16)lo.x; afr[kk][1] = (__bf16)lo.y;
            afr[kk][2] = (__bf16)lo.z; afr[kk][3] = (__bf16)lo.w;
            afr[kk][4] = (__bf16)hi.x; afr[kk][5] = (__bf16)hi.y;
            afr[kk][6] = (__bf16)hi.z; afr[kk][7] = (__bf16)hi.w;
        }
        f32x4v acc[4];
#pragma unroll
        for (int ct = 0; ct < 4; ++ct)
            acc[ct] = (f32x4v){bval[ct], bval[ct], bval[ct], bval[ct]};
#pragma unroll
        for (int ct = 0; ct < 4; ++ct)
#pragma unroll
            for (int kk = 0; kk < 4; ++kk)
                acc[ct] = __builtin_amdgcn_mfma_f32_16x16x32_bf16(
                              afr[kk], bfr[ct][kk], acc[ct], 0, 0, 0);

        const size_t orow0 = rowbase + rt * 16 + kq * 4;
#pragma unroll
        for (int ct = 0; ct < 4; ++ct) {
            const int col = w * 64 + ct * 16 + r16;
#pragma unroll
            for (int rr = 0; rr < 4; ++rr)
                xw[(orow0 + rr) * G4 + col] = (__bf16)acc[ct][rr];
        }
    }
}

// ---------------------------------------------------------------------------
// K2: LSTM scan, 4 cooperating waves per 16-batch group, 1 group/block,
// 16 blocks. R13 structure; xw gathered from the NATURAL layout via
// per-lane-addressed global_load_lds (wave w issues instrs i=2w,2w+1 each
// step -> batch pairs 4w..4w+3; data is cross-wave, so superstep top adds
// one s_barrier after vmcnt(16) to make all waves' loads visible).
// ---------------------------------------------------------------------------
#define SST 8   // steps per superstep

__global__ __launch_bounds__(256, 1)
void k2_scan(const __bf16* __restrict__ xw, const float* __restrict__ U,
             float* __restrict__ hout) {
    const int tid = threadIdx.x;
    const int w   = tid >> 6;       // wave 0..3
    const int l   = tid & 63;
    const int kq  = l >> 4;
    const int m   = l & 15;
    const int s_  = w >> 1, d2 = w & 1;
    const int G   = blockIdx.x;     // group 0..15

    __shared__ __align__(16) unsigned char ring[2][SST][8192];     // 128KB
    __shared__ __align__(16) __bf16 hx[2][16][72];                 // 4.5KB

    // A-frags: au[g][ks][j] = sc_g * U[32ks + 8kq + j][origcol(64g+16w+m)]
    bf16x8 au[4][2];
#pragma unroll
    for (int g = 0; g < 4; ++g) {
        const float sc = (g == 2) ? 1.f : 0.2f;
        const int col = rho_origcol(64 * g + 16 * w + m);
#pragma unroll
        for (int ks = 0; ks < 2; ++ks)
#pragma unroll
            for (int j = 0; j < 8; ++j)
                au[g][ks][j] = (__bf16)(sc * U[(size_t)(ks * 32 + kq * 8 + j) * G4 + col]);
    }

    float c4[4]  = {0.f, 0.f, 0.f, 0.f};
    float hv4[4] = {0.f, 0.f, 0.f, 0.f};

    // zero hx[1] (read by the very first step, rp = 1)
    {
        const bf16x4 z4 = {(__bf16)0.f, (__bf16)0.f, (__bf16)0.f, (__bf16)0.f};
        *(bf16x4*)&hx[1][m][32 * s_ + 8 * kq + 4 * d2] = z4;
    }

    // per-lane DMA source offsets for this wave's instrs i = 2w + j, j=0,1:
    //   m' = 2i + (l>>5), sch = ((l&31) - m') & 31
    //   src = xw + (16G + m')*524288 + sch*16 + t*512
    const char* xwc = (const char*)xw;
    const char* src_j[2];
#pragma unroll
    for (int j = 0; j < 2; ++j) {
        const int i  = 2 * w + j;
        const int mp = 2 * i + (l >> 5);
        const int sch = ((l & 31) - mp) & 31;
        src_j[j] = xwc + (size_t)(16 * G + mp) * 524288 + (size_t)sch * 16;
    }
    // LDS dest offsets (wave-uniform): instr i -> slot + i*1024
    // C-init read offsets (loop-invariant per lane):
    int rd_off[4];
#pragma unroll
    for (int g = 0; g < 4; ++g)
        rd_off[g] = m * 512 + (((8 * g + 2 * w + (kq >> 1) + m) & 31) << 4)
                    + ((kq & 1) << 3);

    // prologue: issue buf0 (steps 0..7) and buf1 (steps 8..15): 16/wave
#pragma unroll
    for (int buf = 0; buf < 2; ++buf)
#pragma unroll
        for (int stp = 0; stp < SST; ++stp)
#pragma unroll
            for (int j = 0; j < 2; ++j)
                gld_lds16(src_j[j] + (size_t)(buf * SST + stp) * 512,
                          &ring[buf][stp][(2 * w + j) * 1024]);
    __syncthreads();   // once: drains prologue DMAs + publishes hx[1] zeros

    uint2  dz[4];
    f32x4v accN[4];
    bf16x8 bh0, bh1;

    for (int S = 0; S < Tt / SST; ++S) {
        const int cur = S & 1;

        // own 16 superstep-S loads done; barrier -> ALL waves' loads visible
        asm volatile("s_waitcnt vmcnt(16)" ::: "memory");
        __builtin_amdgcn_sched_barrier(0);
        __builtin_amdgcn_s_barrier();
        __builtin_amdgcn_sched_barrier(0);

        // superstep-top C-init for stp 0
#pragma unroll
        for (int g = 0; g < 4; ++g)
            dz[g] = *(const uint2*)&ring[cur][0][rd_off[g]];
#pragma unroll
        for (int g = 0; g < 4; ++g) {
            accN[g][0] = __builtin_bit_cast(float, dz[g].x << 16);
            accN[g][1] = __builtin_bit_cast(float, dz[g].x & 0xFFFF0000u);
            accN[g][2] = __builtin_bit_cast(float, dz[g].y << 16);
            accN[g][3] = __builtin_bit_cast(float, dz[g].y & 0xFFFF0000u);
        }

#pragma unroll
        for (int stp = 0; stp < SST; ++stp) {
            const int rp = (stp + 1) & 1;

            bh0 = *(const bf16x8*)&hx[rp][m][8 * kq];
            bh1 = *(const bf16x8*)&hx[rp][m][32 + 8 * kq];

            f32x4v acc[4];
#pragma unroll
            for (int g = 0; g < 4; ++g) {
                acc[g] = __builtin_amdgcn_mfma_f32_16x16x32_bf16(au[g][0], bh0, accN[g], 0, 0, 0);
                acc[g] = __builtin_amdgcn_mfma_f32_16x16x32_bf16(au[g][1], bh1, acc[g], 0, 0, 0);
            }

            bf16x4 hb;
#pragma unroll
            for (int r = 0; r < 4; ++r) {
                const float gi = __builtin_amdgcn_fmed3f(acc[0][r], 0.f, 1.f);
                const float gf = __builtin_amdgcn_fmed3f(acc[1][r], 0.f, 1.f);
                const float gg = fmaxf(acc[2][r], 0.f);
                const float go = __builtin_amdgcn_fmed3f(acc[3][r], 0.f, 1.f);
                c4[r] = fmaf(gf, c4[r], gi * gg);
                hv4[r] = go * fmaxf(c4[r], 0.f);
                hb[r] = (__bf16)hv4[r];
            }

            *(bf16x4*)&hx[stp & 1][m][32 * s_ + 8 * kq + 4 * d2] = hb;

            if (stp < SST - 1) {
#pragma unroll
                for (int g = 0; g < 4; ++g)
                    dz[g] = *(const uint2*)&ring[cur][stp + 1][rd_off[g]];
                asm volatile("s_waitcnt lgkmcnt(4)" ::: "memory");  // write drained
            } else {
                asm volatile("s_waitcnt lgkmcnt(0)" ::: "memory");
            }
            __builtin_amdgcn_sched_barrier(0);
            __builtin_amdgcn_s_barrier();
            __builtin_amdgcn_sched_barrier(0);

            if (stp < SST - 1) {
#pragma unroll
                for (int g = 0; g < 4; ++g) {
                    accN[g][0] = __builtin_bit_cast(float, dz[g].x << 16);
                    accN[g][1] = __builtin_bit_cast(float, dz[g].x & 0xFFFF0000u);
                    accN[g][2] = __builtin_bit_cast(float, dz[g].y << 16);
                    accN[g][3] = __builtin_bit_cast(float, dz[g].y & 0xFFFF0000u);
                }
            }
        }

        // issue superstep S+2 into buf[cur] (all reads retired: stp7 barrier)
        {
            int tn0 = (S + 2) * SST;
            if (tn0 > Tt - SST) tn0 = Tt - SST;
#pragma unroll
            for (int stp = 0; stp < SST; ++stp)
#pragma unroll
                for (int j = 0; j < 2; ++j)
                    gld_lds16(src_j[j] + (size_t)(tn0 + stp) * 512,
                              &ring[cur][stp][(2 * w + j) * 1024]);
        }
    }

#pragma unroll
    for (int r = 0; r < 4; ++r)
        hout[(size_t)(G * 16 + m) * Hh + 32 * s_ + 8 * kq + 4 * d2 + r] = hv4[r];
}

// ---------------------------------------------------------------------------
// K3: out[r,:] = softmax(h[r,:] @ Wd + bd). One block, thread = batch row.
// ---------------------------------------------------------------------------
__global__ __launch_bounds__(256)
void k3_dense(const float* __restrict__ hin, const float* __restrict__ Wd,
              const float* __restrict__ bd, float* __restrict__ out) {
    __shared__ float wd[Hh * NOUT];
    __shared__ float bds[NOUT];
    for (int i = threadIdx.x; i < Hh * NOUT; i += blockDim.x) wd[i] = Wd[i];
    if (threadIdx.x < NOUT) bds[threadIdx.x] = bd[threadIdx.x];
    __syncthreads();

    const int r = threadIdx.x;
    if (r < Bsz) {
        float hrow[Hh];
#pragma unroll
        for (int j = 0; j < Hh; ++j) hrow[j] = hin[(size_t)r * Hh + j];
        float logits[NOUT];
#pragma unroll
        for (int o = 0; o < NOUT; ++o) {
            float acc = bds[o];
#pragma unroll
            for (int j = 0; j < Hh; ++j) acc = fmaf(hrow[j], wd[j * NOUT + o], acc);
            logits[o] = acc;
        }
        float mx = logits[0];
#pragma unroll
        for (int o = 1; o < NOUT; ++o) mx = fmaxf(mx, logits[o]);
        float s = 0.f;
#pragma unroll
        for (int o = 0; o < NOUT; ++o) { logits[o] = expf(logits[o] - mx); s += logits[o]; }
        const float inv = 1.f / s;
#pragma unroll
        for (int o = 0; o < NOUT; ++o) out[(size_t)r * NOUT + o] = logits[o] * inv;
    }
}

// ---------------------------------------------------------------------------
extern "C" void kernel_launch(void* const* d_in, const int* in_sizes, int n_in,
                              void* d_out, int out_size, void* d_ws, size_t ws_size,
                              hipStream_t stream) {
    const float* x  = (const float*)d_in[0];
    const float* W  = (const float*)d_in[1];
    const float* U  = (const float*)d_in[2];
    const float* b  = (const float*)d_in[3];
    const float* Wd = (const float*)d_in[4];
    const float* bd = (const float*)d_in[5];
    float* out = (float*)d_out;

    const size_t xw_bytes = (size_t)Bsz * Tt * G4 * sizeof(__bf16);   // 128 MiB
    __bf16* xw    = (__bf16*)d_ws;
    float*  hbuf  = (float*)((char*)d_ws + xw_bytes);                 // 64 KB
    __bf16* Wt    = (__bf16*)((char*)hbuf + (size_t)Bsz * Hh * sizeof(float));
    float*  bias2 = (float*)((char*)Wt + (size_t)G4 * Dd * sizeof(__bf16));

    k0_prep<<<G4, Dd, 0, stream>>>(W, b, Wt, bias2);
    k1_mfma<<<(Bsz * Tt) / (16 * K1_RT), 256, 0, stream>>>(x, Wt, bias2, xw);
    k2_scan<<<Bsz / 16, 256, 0, stream>>>(xw, U, hbuf);
    k3_dense<<<1, 256, 0, stream>>>(hbuf, Wd, bd, out);
}